// Round 15
// baseline (76.639 us; speedup 1.0000x reference)
//
#include <hip/hip_runtime.h>
#include <cstddef>

#define NSAMP 16
#define HW 409600
#define CPRED 6
#define EPS 1e-6
#define BPS1 50        // blocks/sample, pass1/ref2c (50 * 8192 = 409600)
#define BPSD 100       // blocks/sample, text-dice
#define NBA 64         // level-1 bins (top 6 bits)
#define SH1 26
#define NBB 8192       // radix bins (13 bits)
#define REG 8192       // per-block key region

__device__ __forceinline__ unsigned sortkey(float f) {
    unsigned b = __float_as_uint(f);
    return (b & 0x80000000u) ? ~b : (b | 0x80000000u);   // larger float -> larger key
}
__device__ __forceinline__ float inv_sortkey(unsigned k) {
    unsigned b = (k & 0x80000000u) ? (k ^ 0x80000000u) : ~k;
    return __uint_as_float(b);
}
__device__ __forceinline__ float sigmoidf(float x) {
    return 1.0f / (1.0f + __expf(-x));
}

// Pass 1: stream ALL 5 planes (cold). Stats partials (pos/neg/minkey/64-bin
// hist) + kernel-dice partial sums (mask is OHEM-independent). Plain stores.
__global__ void k_pass1(const float* __restrict__ preds,
                        const float* __restrict__ targets,
                        const float* __restrict__ eff,
                        unsigned* __restrict__ histP,   // [16][50][64]
                        unsigned* __restrict__ posP,    // [16][50]
                        unsigned* __restrict__ negP,
                        unsigned* __restrict__ nkP,     // max of ~key
                        double* __restrict__ partK) {   // [16][50][3]
    const int n = blockIdx.y, x = blockIdx.x;
    const int tid = threadIdx.x, wave = tid >> 6, lane = tid & 63;
    __shared__ unsigned h[4][NBA];
    __shared__ unsigned wred[12];
    __shared__ double dws[12];
    ((unsigned*)h)[tid] = 0;           // 4*64 == 256
    __syncthreads();
    const float* pr0 = preds + (size_t)n * CPRED * HW;
    const float* tg0 = targets + (size_t)n * 2 * HW;
    const float4* p04 = (const float4*)pr0;
    const float4* p14 = (const float4*)(pr0 + HW);
    const float4* t04 = (const float4*)tg0;
    const float4* t14 = (const float4*)(tg0 + HW);
    const float4* e4  = (const float4*)(eff + (size_t)n * HW);
    const int base = x * 2048;
    unsigned lp = 0, ln = 0, mx = 0;
    float sPGk = 0.f, sP2k = 0.f, sG2k = 0.f;
#pragma unroll
    for (int k = 0; k < 8; k++) {
        int i = base + k * 256 + tid;
        float4 p = p04[i], q = p14[i], t = t04[i], u = t14[i], e = e4[i];
        float pa[4] = {p.x, p.y, p.z, p.w};
        float pb[4] = {q.x, q.y, q.z, q.w};
        float ta[4] = {t.x, t.y, t.z, t.w};
        float ua[4] = {u.x, u.y, u.z, u.w};
        float ea[4] = {e.x, e.y, e.z, e.w};
#pragma unroll
        for (int j = 0; j < 4; j++) {
            lp += (ta[j] > 0.5f && ea[j] > 0.5f) ? 1u : 0u;
            if (ta[j] <= 0.5f) {
                ln++;
                unsigned key = sortkey(pa[j]);
                atomicAdd(&h[wave][key >> SH1], 1u);
                unsigned nk = ~key;
                mx = (nk > mx) ? nk : mx;
            }
            // kernel-dice: mask independent of OHEM threshold
            float pt = sigmoidf(pa[j]);
            float pk = sigmoidf(pb[j]);
            float tbk = (ua[j] > 0.5f) ? 1.f : 0.f;
            float mk = (pt > 0.5f && ea[j] > 0.5f) ? 1.f : 0.f;
            float Pk = pk * mk, Tk = tbk * mk;
            sPGk += Pk * Tk; sP2k += Pk * Pk; sG2k += Tk * Tk;
        }
    }
    for (int o = 32; o; o >>= 1) {
        lp += __shfl_down(lp, o, 64);
        ln += __shfl_down(ln, o, 64);
        unsigned om = __shfl_down(mx, o, 64);
        mx = (om > mx) ? om : mx;
        sPGk += __shfl_down(sPGk, o, 64);
        sP2k += __shfl_down(sP2k, o, 64);
        sG2k += __shfl_down(sG2k, o, 64);
    }
    if (lane == 0) {
        wred[wave] = lp; wred[4 + wave] = ln; wred[8 + wave] = mx;
        dws[wave * 3 + 0] = sPGk; dws[wave * 3 + 1] = sP2k; dws[wave * 3 + 2] = sG2k;
    }
    __syncthreads();
    const int bi = n * BPS1 + x;
    if (tid == 0) {
        posP[bi] = wred[0] + wred[1] + wred[2] + wred[3];
        negP[bi] = wred[4] + wred[5] + wred[6] + wred[7];
        unsigned m = wred[8];
        m = (wred[9] > m) ? wred[9] : m;
        m = (wred[10] > m) ? wred[10] : m;
        m = (wred[11] > m) ? wred[11] : m;
        nkP[bi] = m;
    }
    if (tid < 3)
        partK[(size_t)bi * 3 + tid] = dws[tid] + dws[3 + tid] + dws[6 + tid] + dws[9 + tid];
    if (tid < NBA)
        histP[(size_t)bi * NBA + tid] = h[0][tid] + h[1][tid] + h[2][tid] + h[3][tid];
}

// Pass 2 (general path only): recompute need/b1 from partials; early-exit on
// shortcut (this data: always). Else compact bucket-b1 keys (own region).
__global__ void k_ref2c(const float* __restrict__ preds,
                        const float* __restrict__ targets,
                        const unsigned* __restrict__ posP,
                        const unsigned* __restrict__ negP,
                        const unsigned* __restrict__ histP,
                        unsigned* __restrict__ keys,    // [16][50][8192]
                        unsigned* __restrict__ cntP) {  // [16][50]
    const int n = blockIdx.y, x = blockIdx.x;
    const int tid = threadIdx.x, wave = tid >> 6, lane = tid & 63;
    __shared__ unsigned sP, sN;
    __shared__ unsigned hsum[NBA];
    __shared__ int s_need;
    __shared__ unsigned s_b1;
    __shared__ unsigned kbuf[4][2048];
    __shared__ unsigned kcnt[4];
    if (tid == 0) { sP = 0; sN = 0; }
    __syncthreads();
    if (tid < BPS1) {
        atomicAdd(&sP, posP[n * BPS1 + tid]);
        atomicAdd(&sN, negP[n * BPS1 + tid]);
    }
    if (tid < NBA) {
        unsigned s = 0;
        for (int xx = 0; xx < BPS1; xx++) s += histP[(size_t)(n * BPS1 + xx) * NBA + tid];
        hsum[tid] = s;
    }
    __syncthreads();
    if (tid == 0) {
        const unsigned P = sP, NC = sN;
        const unsigned nn = (P * 3u < NC) ? P * 3u : NC;
        const bool need = (P > 0 && nn > 0 && nn < NC);
        s_need = need ? 1 : 0;
        if (need) {
            unsigned cum = 0; int b;
            for (b = NBA - 1;; b--) { if (cum + hsum[b] >= nn) break; cum += hsum[b]; }
            s_b1 = (unsigned)b;
        }
    }
    __syncthreads();
    if (!s_need) {
        if (tid == 0) cntP[n * BPS1 + x] = 0;
        return;
    }
    const unsigned B1 = s_b1;
    const float4* p4 = (const float4*)(preds + (size_t)n * CPRED * HW);
    const float4* t4 = (const float4*)(targets + (size_t)n * 2 * HW);
    const unsigned long long lmask = (1ull << lane) - 1ull;
    unsigned run = 0;
    const int base = x * 2048;
#pragma unroll
    for (int k = 0; k < 8; k++) {
        int i = base + k * 256 + tid;
        float4 p = p4[i], t = t4[i];
        float pa[4] = {p.x, p.y, p.z, p.w};
        float ta[4] = {t.x, t.y, t.z, t.w};
#pragma unroll
        for (int j = 0; j < 4; j++) {
            unsigned key = sortkey(pa[j]);
            const bool m = (ta[j] <= 0.5f) && ((key >> SH1) == B1);
            unsigned long long bm = __ballot(m);
            if (m) {
                int rank = __popcll(bm & lmask);
                kbuf[wave][run + rank] = key;
            }
            run += (unsigned)__popcll(bm);
        }
    }
    if (lane == 0) kcnt[wave] = run;
    __syncthreads();
    unsigned off = 0;
    for (int w = 0; w < wave; w++) off += kcnt[w];
    if (tid == 0) cntP[n * BPS1 + x] = kcnt[0] + kcnt[1] + kcnt[2] + kcnt[3];
    unsigned* kout = keys + (size_t)(n * BPS1 + x) * REG;
    const unsigned cnt = kcnt[wave];
    for (unsigned i = lane; i < cnt; i += 64) kout[off + i] = kbuf[wave][i];
}

// Pass 3: one block per sample. Shortcut thr = min negative; general path:
// exact 13+13-bit select over compacted keys.
__global__ void k_sel(const unsigned* __restrict__ posP,
                      const unsigned* __restrict__ negP,
                      const unsigned* __restrict__ nkP,
                      const unsigned* __restrict__ histP,
                      const unsigned* __restrict__ keys,
                      const unsigned* __restrict__ cntP,
                      float* __restrict__ thrg,
                      unsigned* __restrict__ fbg) {
    const int n = blockIdx.x;
    const int tid = threadIdx.x;
    __shared__ unsigned hist[NBB];      // 32 KB
    __shared__ unsigned chunk[256];
    __shared__ unsigned sP, sN, sMX;
    __shared__ int s_need;
    __shared__ unsigned s_b1, s_rem1, s_b2, s_rem2;
    if (tid == 0) { sP = 0; sN = 0; sMX = 0; }
    __syncthreads();
    if (tid < BPS1) {
        atomicAdd(&sP, posP[n * BPS1 + tid]);
        atomicAdd(&sN, negP[n * BPS1 + tid]);
        atomicMax(&sMX, nkP[n * BPS1 + tid]);
    }
    if (tid < NBA) {
        unsigned s = 0;
        for (int xx = 0; xx < BPS1; xx++) s += histP[(size_t)(n * BPS1 + xx) * NBA + tid];
        hist[tid] = s;
    }
    __syncthreads();
    if (tid == 0) {
        const unsigned P = sP, NC = sN;
        const unsigned nn = (P * 3u < NC) ? P * 3u : NC;
        const bool fb = (P == 0 || nn == 0);
        const bool need = (!fb && nn < NC);
        s_need = need ? 1 : 0;
        if (!need) {
            fbg[n] = fb ? 1u : 0u;
            thrg[n] = fb ? -INFINITY : inv_sortkey(~sMX);
        } else {
            fbg[n] = 0u;
            unsigned cum = 0; int b;
            for (b = NBA - 1;; b--) { if (cum + hist[b] >= nn) break; cum += hist[b]; }
            s_b1 = (unsigned)b; s_rem1 = nn - cum;
        }
    }
    __syncthreads();
    if (!s_need) return;
    for (int i = tid; i < NBB; i += 256) hist[i] = 0;
    __syncthreads();
    for (int xx = 0; xx < BPS1; xx++) {
        const unsigned c = cntP[n * BPS1 + xx];
        const unsigned* kin = keys + (size_t)(n * BPS1 + xx) * REG;
        for (unsigned i = tid; i < c; i += 256)
            atomicAdd(&hist[(kin[i] >> 13) & 0x1FFFu], 1u);
    }
    __syncthreads();
    {
        unsigned cs = 0;
#pragma unroll
        for (int j = 0; j < 32; j++) cs += hist[tid * 32 + j];
        chunk[tid] = cs;
    }
    __syncthreads();
    if (tid == 0) {
        const unsigned r = s_rem1;
        unsigned cum = 0; int c;
        for (c = 255;; c--) { if (cum + chunk[c] >= r) break; cum += chunk[c]; }
        int b;
        for (b = c * 32 + 31;; b--) { unsigned hv = hist[b]; if (cum + hv >= r) break; cum += hv; }
        s_b2 = (unsigned)b; s_rem2 = r - cum;
    }
    __syncthreads();
    const unsigned B2 = s_b2;
    for (int i = tid; i < NBB; i += 256) hist[i] = 0;
    __syncthreads();
    for (int xx = 0; xx < BPS1; xx++) {
        const unsigned c = cntP[n * BPS1 + xx];
        const unsigned* kin = keys + (size_t)(n * BPS1 + xx) * REG;
        for (unsigned i = tid; i < c; i += 256) {
            unsigned key = kin[i];
            if (((key >> 13) & 0x1FFFu) == B2) atomicAdd(&hist[key & 0x1FFFu], 1u);
        }
    }
    __syncthreads();
    {
        unsigned cs = 0;
#pragma unroll
        for (int j = 0; j < 32; j++) cs += hist[tid * 32 + j];
        chunk[tid] = cs;
    }
    __syncthreads();
    if (tid == 0) {
        const unsigned r = s_rem2;
        unsigned cum = 0; int c;
        for (c = 255;; c--) { if (cum + chunk[c] >= r) break; cum += chunk[c]; }
        int b;
        for (b = c * 32 + 31;; b--) { unsigned hv = hist[b]; if (cum + hv >= r) break; cum += hv; }
        thrg[n] = inv_sortkey((s_b1 << SH1) | (B2 << 13) | (unsigned)b);
    }
}

// Pass 4: TEXT dice only (p0/t0/eff, all L3-hot after pass1).
__global__ void k_dicet(const float* __restrict__ preds,
                        const float* __restrict__ targets,
                        const float* __restrict__ eff,
                        const float* __restrict__ thrg,
                        const unsigned* __restrict__ fbg,
                        double* __restrict__ partT) {   // [16][100][3]
    const int n = blockIdx.y;
    const int tid = threadIdx.x, wave = tid >> 6, lane = tid & 63;
    __shared__ double dws[12];
    const float th = thrg[n];
    const bool fallback = (fbg[n] != 0);
    const float4* p04 = (const float4*)(preds + (size_t)n * CPRED * HW);
    const float4* t04 = (const float4*)(targets + (size_t)n * 2 * HW);
    const float4* e4  = (const float4*)(eff + (size_t)n * HW);
    float sPG = 0.f, sP2 = 0.f, sG2 = 0.f;
    const int base = blockIdx.x * 1024;
#pragma unroll
    for (int k = 0; k < 4; k++) {
        int i = base + k * 256 + tid;
        float4 a = p04[i], t = t04[i], e = e4[i];
        float pa[4] = {a.x, a.y, a.z, a.w};
        float ta[4] = {t.x, t.y, t.z, t.w};
        float ea[4] = {e.x, e.y, e.z, e.w};
#pragma unroll
        for (int j = 0; j < 4; j++) {
            float pt = sigmoidf(pa[j]);
            float tbt = (ta[j] > 0.5f) ? 1.f : 0.f;
            float m;
            if (fallback) m = ea[j];
            else m = (((pa[j] >= th) || (ta[j] > 0.5f)) && (ea[j] > 0.5f)) ? 1.f : 0.f;
            float Pm = pt * m, Tm = tbt * m;
            sPG += Pm * Tm; sP2 += Pm * Pm; sG2 += Tm * Tm;
        }
    }
    for (int o = 32; o; o >>= 1) {
        sPG += __shfl_down(sPG, o, 64);
        sP2 += __shfl_down(sP2, o, 64);
        sG2 += __shfl_down(sG2, o, 64);
    }
    if (lane == 0) {
        dws[wave * 3 + 0] = sPG; dws[wave * 3 + 1] = sP2; dws[wave * 3 + 2] = sG2;
    }
    __syncthreads();
    if (tid < 3) {
        double v = dws[tid] + dws[3 + tid] + dws[6 + tid] + dws[9 + tid];
        partT[((size_t)n * BPSD + blockIdx.x) * 3 + tid] = v;
    }
}

// Pass 5: reduce text partials (100/sample) + kernel partials (50/sample).
__global__ void k_final(const double* __restrict__ partT,
                        const double* __restrict__ partK,
                        float* __restrict__ out) {
    __shared__ double ssum[96];
    const int t = threadIdx.x;
    if (t < 96) {
        const int n = t / 6, c = t % 6;
        double a = 0.0;
        if (c < 3) {
            for (int b = 0; b < BPSD; b++) a += partT[((size_t)n * BPSD + b) * 3 + c];
        } else {
            for (int b = 0; b < BPS1; b++) a += partK[((size_t)n * BPS1 + b) * 3 + (c - 3)];
        }
        ssum[t] = a;
    }
    __syncthreads();
    if (t < NSAMP) {
        const double* s = &ssum[t * 6];
        out[t]         = (float)(1.0 - 2.0 * s[0] / (s[1] + s[2] + EPS));
        out[NSAMP + t] = (float)(1.0 - 2.0 * s[3] / (s[4] + s[5] + EPS));
    }
}

extern "C" void kernel_launch(void* const* d_in, const int* in_sizes, int n_in,
                              void* d_out, int out_size, void* d_ws, size_t ws_size,
                              hipStream_t stream) {
    const float* preds = (const float*)d_in[0];
    const float* targets = (const float*)d_in[1];
    const float* eff = (const float*)d_in[2];
    float* out = (float*)d_out;

    // Everything plain-stored each call -> NO zero kernel.
    char* ws = (char*)d_ws;
    unsigned* histP = (unsigned*)ws;                          // 16*50*64*4 = 204800
    unsigned* posP  = (unsigned*)(ws + 204800);               // 800*4 each
    unsigned* negP  = posP + NSAMP * BPS1;
    unsigned* nkP   = negP + NSAMP * BPS1;
    unsigned* cntP  = nkP + NSAMP * BPS1;                     // ends 217600
    float*    thrg  = (float*)(ws + 217600);
    unsigned* fbg   = (unsigned*)(thrg + NSAMP);              // ends 217728
    double* partT   = (double*)(ws + 217728);                 // 16*100*3*8 = 38400
    double* partK   = (double*)(ws + 256128);                 // 16*50*3*8 = 19200
    unsigned* keys  = (unsigned*)(ws + 275328);               // 26.2 MB

    dim3 b1(BPS1, NSAMP);
    dim3 bd(BPSD, NSAMP);
    k_pass1<<<b1, 256, 0, stream>>>(preds, targets, eff, histP, posP, negP, nkP, partK);
    k_ref2c<<<b1, 256, 0, stream>>>(preds, targets, posP, negP, histP, keys, cntP);
    k_sel  <<<NSAMP, 256, 0, stream>>>(posP, negP, nkP, histP, keys, cntP, thrg, fbg);
    k_dicet<<<bd, 256, 0, stream>>>(preds, targets, eff, thrg, fbg, partT);
    k_final<<<1, 128, 0, stream>>>(partT, partK, out);
}

// Round 16
// 61.005 us; speedup vs baseline: 1.2563x; 1.2563x over previous
//
#include <hip/hip_runtime.h>
#include <cstddef>

#define NSAMP 16
#define HW 409600
#define CPRED 6
#define EPS 1e-6
#define BPS1 50        // blocks/sample, streaming passes (50 * 8192 = 409600)
#define BPSD 100       // blocks/sample, dice
#define NBA 64         // level-1 bins (top 6 bits)
#define SH1 26
#define NBB 8192       // level-2/3 bins (13 bits each)
#define REG 8192       // per-block key region (block max elements)

__device__ __forceinline__ unsigned sortkey(float f) {
    unsigned b = __float_as_uint(f);
    return (b & 0x80000000u) ? ~b : (b | 0x80000000u);   // larger float -> larger key
}
__device__ __forceinline__ float inv_sortkey(unsigned k) {
    unsigned b = (k & 0x80000000u) ? (k ^ 0x80000000u) : ~k;
    return __uint_as_float(b);
}
__device__ __forceinline__ float sigmoidf(float x) {
    return 1.0f / (1.0f + __expf(-x));
}

// Pass 1: stream p0/t0/eff. Per-block PLAIN stores (no zeroing, no global
// atomics): pos, neg, max(~key) over negatives, 64-bin top-6 histogram.
__global__ void k_pass1(const float* __restrict__ preds,
                        const float* __restrict__ targets,
                        const float* __restrict__ eff,
                        unsigned* __restrict__ histP,   // [16][50][64]
                        unsigned* __restrict__ posP,    // [16][50]
                        unsigned* __restrict__ negP,
                        unsigned* __restrict__ nkP) {   // max of ~key
    const int n = blockIdx.y, x = blockIdx.x;
    const int tid = threadIdx.x, wave = tid >> 6, lane = tid & 63;
    __shared__ unsigned h[4][NBA];
    __shared__ unsigned wred[12];
    ((unsigned*)h)[tid] = 0;           // 4*64 == 256
    __syncthreads();
    const float4* p4 = (const float4*)(preds + (size_t)n * CPRED * HW);
    const float4* t4 = (const float4*)(targets + (size_t)n * 2 * HW);
    const float4* e4 = (const float4*)(eff + (size_t)n * HW);
    const int base = x * 2048;
    unsigned lp = 0, ln = 0, mx = 0;
#pragma unroll
    for (int k = 0; k < 8; k++) {
        int i = base + k * 256 + tid;
        float4 p = p4[i], t = t4[i], e = e4[i];
        float pa[4] = {p.x, p.y, p.z, p.w};
        float ta[4] = {t.x, t.y, t.z, t.w};
        float ea[4] = {e.x, e.y, e.z, e.w};
#pragma unroll
        for (int j = 0; j < 4; j++) {
            lp += (ta[j] > 0.5f && ea[j] > 0.5f) ? 1u : 0u;
            if (ta[j] <= 0.5f) {
                ln++;
                unsigned key = sortkey(pa[j]);
                atomicAdd(&h[wave][key >> SH1], 1u);
                unsigned nk = ~key;
                mx = (nk > mx) ? nk : mx;
            }
        }
    }
    for (int o = 32; o; o >>= 1) {
        lp += __shfl_down(lp, o, 64);
        ln += __shfl_down(ln, o, 64);
        unsigned om = __shfl_down(mx, o, 64);
        mx = (om > mx) ? om : mx;
    }
    if (lane == 0) { wred[wave] = lp; wred[4 + wave] = ln; wred[8 + wave] = mx; }
    __syncthreads();
    const int bi = n * BPS1 + x;
    if (tid == 0) {
        posP[bi] = wred[0] + wred[1] + wred[2] + wred[3];
        negP[bi] = wred[4] + wred[5] + wred[6] + wred[7];
        unsigned m = wred[8];
        m = (wred[9] > m) ? wred[9] : m;
        m = (wred[10] > m) ? wred[10] : m;
        m = (wred[11] > m) ? wred[11] : m;
        nkP[bi] = m;
    }
    if (tid < NBA)
        histP[(size_t)bi * NBA + tid] = h[0][tid] + h[1][tid] + h[2][tid] + h[3][tid];
}

// Pass 2 (general path only): each block recomputes nn/need + b1 from the tiny
// partials, early-exits when the shortcut applies (this benchmark: always).
// Else compacts bucket-b1 negatives' keys into its OWN region (no atomics).
__global__ void k_ref2c(const float* __restrict__ preds,
                        const float* __restrict__ targets,
                        const unsigned* __restrict__ posP,
                        const unsigned* __restrict__ negP,
                        const unsigned* __restrict__ histP,
                        unsigned* __restrict__ keys,    // [16][50][8192]
                        unsigned* __restrict__ cntP) {  // [16][50]
    const int n = blockIdx.y, x = blockIdx.x;
    const int tid = threadIdx.x, wave = tid >> 6, lane = tid & 63;
    __shared__ unsigned sP, sN;
    __shared__ unsigned hsum[NBA];
    __shared__ int s_need;
    __shared__ unsigned s_b1;
    __shared__ unsigned kbuf[4][2048];
    __shared__ unsigned kcnt[4];
    if (tid == 0) { sP = 0; sN = 0; }
    __syncthreads();
    if (tid < BPS1) {
        atomicAdd(&sP, posP[n * BPS1 + tid]);
        atomicAdd(&sN, negP[n * BPS1 + tid]);
    }
    if (tid < NBA) {
        unsigned s = 0;
        for (int xx = 0; xx < BPS1; xx++) s += histP[(size_t)(n * BPS1 + xx) * NBA + tid];
        hsum[tid] = s;
    }
    __syncthreads();
    if (tid == 0) {
        const unsigned P = sP, NC = sN;
        const unsigned nn = (P * 3u < NC) ? P * 3u : NC;
        const bool need = (P > 0 && nn > 0 && nn < NC);
        s_need = need ? 1 : 0;
        if (need) {
            unsigned cum = 0; int b;
            for (b = NBA - 1;; b--) { if (cum + hsum[b] >= nn) break; cum += hsum[b]; }
            s_b1 = (unsigned)b;
        }
    }
    __syncthreads();
    if (!s_need) {
        if (tid == 0) cntP[n * BPS1 + x] = 0;
        return;
    }
    const unsigned B1 = s_b1;
    const float4* p4 = (const float4*)(preds + (size_t)n * CPRED * HW);
    const float4* t4 = (const float4*)(targets + (size_t)n * 2 * HW);
    const unsigned long long lmask = (1ull << lane) - 1ull;
    unsigned run = 0;
    const int base = x * 2048;
#pragma unroll
    for (int k = 0; k < 8; k++) {
        int i = base + k * 256 + tid;
        float4 p = p4[i], t = t4[i];
        float pa[4] = {p.x, p.y, p.z, p.w};
        float ta[4] = {t.x, t.y, t.z, t.w};
#pragma unroll
        for (int j = 0; j < 4; j++) {
            unsigned key = sortkey(pa[j]);
            const bool m = (ta[j] <= 0.5f) && ((key >> SH1) == B1);
            unsigned long long bm = __ballot(m);
            if (m) {
                int rank = __popcll(bm & lmask);
                kbuf[wave][run + rank] = key;
            }
            run += (unsigned)__popcll(bm);
        }
    }
    if (lane == 0) kcnt[wave] = run;
    __syncthreads();
    unsigned off = 0;
    for (int w = 0; w < wave; w++) off += kcnt[w];
    if (tid == 0) cntP[n * BPS1 + x] = kcnt[0] + kcnt[1] + kcnt[2] + kcnt[3];
    unsigned* kout = keys + (size_t)(n * BPS1 + x) * REG;
    const unsigned cnt = kcnt[wave];
    for (unsigned i = lane; i < cnt; i += 64) kout[off + i] = kbuf[wave][i];
}

// Pass 3: one block per sample. Shortcut thr = min negative (from ~key max);
// general path: exact 13+13-bit select over the compacted bucket values.
__global__ void k_sel(const unsigned* __restrict__ posP,
                      const unsigned* __restrict__ negP,
                      const unsigned* __restrict__ nkP,
                      const unsigned* __restrict__ histP,
                      const unsigned* __restrict__ keys,
                      const unsigned* __restrict__ cntP,
                      float* __restrict__ thrg,
                      unsigned* __restrict__ fbg) {
    const int n = blockIdx.x;
    const int tid = threadIdx.x;
    __shared__ unsigned hist[NBB];      // 32 KB
    __shared__ unsigned chunk[256];
    __shared__ unsigned sP, sN, sMX;
    __shared__ int s_need;
    __shared__ unsigned s_b1, s_rem1, s_b2, s_rem2;
    if (tid == 0) { sP = 0; sN = 0; sMX = 0; }
    __syncthreads();
    if (tid < BPS1) {
        atomicAdd(&sP, posP[n * BPS1 + tid]);
        atomicAdd(&sN, negP[n * BPS1 + tid]);
        atomicMax(&sMX, nkP[n * BPS1 + tid]);
    }
    if (tid < NBA) {
        unsigned s = 0;
        for (int xx = 0; xx < BPS1; xx++) s += histP[(size_t)(n * BPS1 + xx) * NBA + tid];
        hist[tid] = s;
    }
    __syncthreads();
    if (tid == 0) {
        const unsigned P = sP, NC = sN;
        const unsigned nn = (P * 3u < NC) ? P * 3u : NC;
        const bool fb = (P == 0 || nn == 0);
        const bool need = (!fb && nn < NC);
        s_need = need ? 1 : 0;
        if (!need) {
            fbg[n] = fb ? 1u : 0u;
            thrg[n] = fb ? -INFINITY : inv_sortkey(~sMX);
        } else {
            fbg[n] = 0u;
            unsigned cum = 0; int b;
            for (b = NBA - 1;; b--) { if (cum + hist[b] >= nn) break; cum += hist[b]; }
            s_b1 = (unsigned)b; s_rem1 = nn - cum;
        }
    }
    __syncthreads();
    if (!s_need) return;
    // Round A: 13-bit digit (key>>13)&0x1FFF over bucket values
    for (int i = tid; i < NBB; i += 256) hist[i] = 0;
    __syncthreads();
    for (int xx = 0; xx < BPS1; xx++) {
        const unsigned c = cntP[n * BPS1 + xx];
        const unsigned* kin = keys + (size_t)(n * BPS1 + xx) * REG;
        for (unsigned i = tid; i < c; i += 256)
            atomicAdd(&hist[(kin[i] >> 13) & 0x1FFFu], 1u);
    }
    __syncthreads();
    {
        unsigned cs = 0;
#pragma unroll
        for (int j = 0; j < 32; j++) cs += hist[tid * 32 + j];
        chunk[tid] = cs;
    }
    __syncthreads();
    if (tid == 0) {
        const unsigned r = s_rem1;
        unsigned cum = 0; int c;
        for (c = 255;; c--) { if (cum + chunk[c] >= r) break; cum += chunk[c]; }
        int b;
        for (b = c * 32 + 31;; b--) { unsigned hv = hist[b]; if (cum + hv >= r) break; cum += hv; }
        s_b2 = (unsigned)b; s_rem2 = r - cum;
    }
    __syncthreads();
    const unsigned B2 = s_b2;
    // Round B: low 13 bits among values with digit == B2
    for (int i = tid; i < NBB; i += 256) hist[i] = 0;
    __syncthreads();
    for (int xx = 0; xx < BPS1; xx++) {
        const unsigned c = cntP[n * BPS1 + xx];
        const unsigned* kin = keys + (size_t)(n * BPS1 + xx) * REG;
        for (unsigned i = tid; i < c; i += 256) {
            unsigned key = kin[i];
            if (((key >> 13) & 0x1FFFu) == B2) atomicAdd(&hist[key & 0x1FFFu], 1u);
        }
    }
    __syncthreads();
    {
        unsigned cs = 0;
#pragma unroll
        for (int j = 0; j < 32; j++) cs += hist[tid * 32 + j];
        chunk[tid] = cs;
    }
    __syncthreads();
    if (tid == 0) {
        const unsigned r = s_rem2;
        unsigned cum = 0; int c;
        for (c = 255;; c--) { if (cum + chunk[c] >= r) break; cum += chunk[c]; }
        int b;
        for (b = c * 32 + 31;; b--) { unsigned hv = hist[b]; if (cum + hv >= r) break; cum += hv; }
        thrg[n] = inv_sortkey((s_b1 << SH1) | (B2 << 13) | (unsigned)b);
    }
}

// Pass 4: dice partial sums (thr/fb are ready scalars now; no staging).
__global__ void k_dice(const float* __restrict__ preds,
                       const float* __restrict__ targets,
                       const float* __restrict__ eff,
                       const float* __restrict__ thrg,
                       const unsigned* __restrict__ fbg,
                       double* __restrict__ partials) {
    const int n = blockIdx.y;
    const int tid = threadIdx.x, wave = tid >> 6, lane = tid & 63;
    __shared__ double dws[24];
    const float th = thrg[n];
    const bool fallback = (fbg[n] != 0);
    const float* pr0 = preds + (size_t)n * CPRED * HW;
    const float* tg0 = targets + (size_t)n * 2 * HW;
    const float4* p04 = (const float4*)pr0;
    const float4* p14 = (const float4*)(pr0 + HW);
    const float4* t04 = (const float4*)tg0;
    const float4* t14 = (const float4*)(tg0 + HW);
    const float4* e4  = (const float4*)(eff + (size_t)n * HW);
    float sPG = 0.f, sP2 = 0.f, sG2 = 0.f, sPGk = 0.f, sP2k = 0.f, sG2k = 0.f;
    const int base = blockIdx.x * 1024;
#pragma unroll
    for (int k = 0; k < 4; k++) {
        int i = base + k * 256 + tid;
        float4 a = p04[i], c4 = p14[i], t = t04[i], u = t14[i], e = e4[i];
        float pa[4] = {a.x, a.y, a.z, a.w};
        float pb[4] = {c4.x, c4.y, c4.z, c4.w};
        float ta[4] = {t.x, t.y, t.z, t.w};
        float ua[4] = {u.x, u.y, u.z, u.w};
        float ea[4] = {e.x, e.y, e.z, e.w};
#pragma unroll
        for (int j = 0; j < 4; j++) {
            float pt = sigmoidf(pa[j]);
            float pk = sigmoidf(pb[j]);
            float tbt = (ta[j] > 0.5f) ? 1.f : 0.f;
            float tbk = (ua[j] > 0.5f) ? 1.f : 0.f;
            float m;
            if (fallback) m = ea[j];
            else m = (((pa[j] >= th) || (ta[j] > 0.5f)) && (ea[j] > 0.5f)) ? 1.f : 0.f;
            float Pm = pt * m, Tm = tbt * m;
            sPG += Pm * Tm; sP2 += Pm * Pm; sG2 += Tm * Tm;
            float mk = (pt > 0.5f && ea[j] > 0.5f) ? 1.f : 0.f;
            float Pk = pk * mk, Tk = tbk * mk;
            sPGk += Pk * Tk; sP2k += Pk * Pk; sG2k += Tk * Tk;
        }
    }
    for (int o = 32; o; o >>= 1) {
        sPG  += __shfl_down(sPG, o, 64);
        sP2  += __shfl_down(sP2, o, 64);
        sG2  += __shfl_down(sG2, o, 64);
        sPGk += __shfl_down(sPGk, o, 64);
        sP2k += __shfl_down(sP2k, o, 64);
        sG2k += __shfl_down(sG2k, o, 64);
    }
    if (lane == 0) {
        dws[wave * 6 + 0] = sPG;  dws[wave * 6 + 1] = sP2;  dws[wave * 6 + 2] = sG2;
        dws[wave * 6 + 3] = sPGk; dws[wave * 6 + 4] = sP2k; dws[wave * 6 + 5] = sG2k;
    }
    __syncthreads();
    if (tid < 6) {
        double v = dws[tid] + dws[6 + tid] + dws[12 + tid] + dws[18 + tid];
        partials[((size_t)n * BPSD + blockIdx.x) * 6 + tid] = v;
    }
}

__global__ void k_final(const double* __restrict__ partials, float* __restrict__ out) {
    __shared__ double ssum[96];
    const int t = threadIdx.x;
    if (t < 96) {
        const int n = t / 6, c = t % 6;
        double a = 0.0;
        for (int b = 0; b < BPSD; b++) a += partials[((size_t)n * BPSD + b) * 6 + c];
        ssum[t] = a;
    }
    __syncthreads();
    if (t < NSAMP) {
        const double* s = &ssum[t * 6];
        out[t]         = (float)(1.0 - 2.0 * s[0] / (s[1] + s[2] + EPS));
        out[NSAMP + t] = (float)(1.0 - 2.0 * s[3] / (s[4] + s[5] + EPS));
    }
}

extern "C" void kernel_launch(void* const* d_in, const int* in_sizes, int n_in,
                              void* d_out, int out_size, void* d_ws, size_t ws_size,
                              hipStream_t stream) {
    const float* preds = (const float*)d_in[0];
    const float* targets = (const float*)d_in[1];
    const float* eff = (const float*)d_in[2];
    float* out = (float*)d_out;

    // Everything plain-stored each call -> NO zero kernel.
    char* ws = (char*)d_ws;
    unsigned* histP = (unsigned*)ws;                          // 16*50*64*4 = 204800
    unsigned* posP  = (unsigned*)(ws + 204800);               // 800*4
    unsigned* negP  = posP + NSAMP * BPS1;
    unsigned* nkP   = negP + NSAMP * BPS1;
    unsigned* cntP  = nkP + NSAMP * BPS1;                     // ends 217600
    float*    thrg  = (float*)(ws + 217600);
    unsigned* fbg   = (unsigned*)(thrg + NSAMP);              // ends 217728
    double* partials = (double*)(ws + 217728);                // 76800 B
    unsigned* keys  = (unsigned*)(ws + 294528);               // 16*50*8192*4 = 26.2 MB

    dim3 b1(BPS1, NSAMP);
    dim3 bd(BPSD, NSAMP);
    k_pass1<<<b1, 256, 0, stream>>>(preds, targets, eff, histP, posP, negP, nkP);
    k_ref2c<<<b1, 256, 0, stream>>>(preds, targets, posP, negP, histP, keys, cntP);
    k_sel  <<<NSAMP, 256, 0, stream>>>(posP, negP, nkP, histP, keys, cntP, thrg, fbg);
    k_dice <<<bd, 256, 0, stream>>>(preds, targets, eff, thrg, fbg, partials);
    k_final<<<1, 128, 0, stream>>>(partials, out);
}